// Round 1
// baseline (220.043 us; speedup 1.0000x reference)
//
#include <hip/hip_runtime.h>
#include <hip/hip_bf16.h>
#include <cstdint>
#include <cstddef>

#define BDIM 16
#define NA   2048
#define NB   2048
#define DD   512

typedef __attribute__((ext_vector_type(8))) short bf16x8;
typedef __attribute__((ext_vector_type(4))) float f32x4;
typedef unsigned short u16;
typedef unsigned int   u32;

__device__ __forceinline__ u16 f2b(float f) {
    u32 u = __float_as_uint(f);
    u = u + 0x7FFFu + ((u >> 16) & 1u);   // RNE
    return (u16)(u >> 16);
}
__device__ __forceinline__ float b2f(u16 h) {
    return __uint_as_float(((u32)h) << 16);
}
__device__ __forceinline__ u32 umin32(u32 a, u32 b) { return a < b ? a : b; }
__device__ __forceinline__ u32 umax32(u32 a, u32 b) { return a > b ? a : b; }

// ---------------------------------------------------------------------------
// Build W2T[n][k] = W[512+k][n]  and  WdT[n][k] = W[k][n] - W[512+k][n]  (bf16)
// ---------------------------------------------------------------------------
__global__ __launch_bounds__(256) void prep_w(const float* __restrict__ W,
                                              u16* __restrict__ W2T,
                                              u16* __restrict__ WdT) {
    int t = blockIdx.x * 256 + threadIdx.x;      // 0 .. 512*512-1
    int n = t >> 9;
    int k = t & 511;
    float w1 = W[(size_t)k * DD + n];
    float w2 = W[(size_t)(DD + k) * DD + n];
    W2T[t] = f2b(w2);
    WdT[t] = f2b(w1 - w2);
}

// ---------------------------------------------------------------------------
// Exact integer top-4 nearest neighbors with lax.top_k tie-breaking
// key = (sqdist << 11) | index   (sqdist < 2^16, index < 2^11)
// ---------------------------------------------------------------------------
__global__ __launch_bounds__(128) void topk_kernel(const int* __restrict__ ca,
                                                   const int* __restrict__ cb,
                                                   int* __restrict__ idx_out,
                                                   float* __restrict__ w_out) {
    __shared__ int cbs[NB * 3];     // 24 KB
    int b = blockIdx.y;
    for (int j = threadIdx.x; j < NB * 3; j += 128)
        cbs[j] = cb[(size_t)b * NB * 3 + j];
    __syncthreads();

    int i = blockIdx.x * 128 + threadIdx.x;
    size_t ai = ((size_t)b * NA + i) * 3;
    int ax = ca[ai], ay = ca[ai + 1], az = ca[ai + 2];

    u32 k0 = 0xFFFFFFFFu, k1 = 0xFFFFFFFFu, k2 = 0xFFFFFFFFu, k3 = 0xFFFFFFFFu;
    #pragma unroll 8
    for (int j = 0; j < NB; ++j) {
        int dx = ax - cbs[3 * j];
        int dy = ay - cbs[3 * j + 1];
        int dz = az - cbs[3 * j + 2];
        u32 s = (u32)(dx * dx + dy * dy + dz * dz);
        u32 key = (s << 11) | (u32)j;
        u32 t0 = umin32(k0, key), m0 = umax32(k0, key); k0 = t0;
        u32 t1 = umin32(k1, m0),  m1 = umax32(k1, m0);  k1 = t1;
        u32 t2 = umin32(k2, m1),  m2 = umax32(k2, m1);  k2 = t2;
        k3 = umin32(k3, m2);
    }
    size_t o = ((size_t)b * NA + i) * 4;
    u32 ks[4] = {k0, k1, k2, k3};
    #pragma unroll
    for (int t = 0; t < 4; ++t) {
        u32 key = ks[t];
        idx_out[o + t] = (int)(key & 2047u);
        float d = sqrtf((float)(key >> 11)) * (1.0f / 128.0f);
        w_out[o + t] = 0.5f - fminf(d, 0.5f);
    }
}

// ---------------------------------------------------------------------------
// C[m][n] (bf16) = A[m][:] (f32, converted to bf16) . BT[n][:] (bf16)
// M x 512 @ (512 x 512)^T ; 128x128 tile, 4 waves, 16x16x32 bf16 MFMA
// ---------------------------------------------------------------------------
#define BK   32
#define PADK 40   // padded LDS row length (bf16 elems) -> 80B row stride

__global__ __launch_bounds__(256) void gemm_f32xbt(const float* __restrict__ A,
                                                   const u16* __restrict__ BT,
                                                   u16* __restrict__ C) {
    __shared__ u16 As[128 * PADK];
    __shared__ u16 Bs[128 * PADK];

    int tid  = threadIdx.x;
    int lane = tid & 63;
    int wave = tid >> 6;
    int wr = (wave >> 1) * 64;      // wave row offset in tile
    int wc = (wave & 1) * 64;       // wave col offset in tile
    int m0 = blockIdx.x * 128;
    int n0 = blockIdx.y * 128;
    int l15 = lane & 15;
    int lk8 = (lane >> 4) * 8;

    f32x4 acc[4][4];
    #pragma unroll
    for (int m = 0; m < 4; ++m)
        #pragma unroll
        for (int n = 0; n < 4; ++n)
            acc[m][n] = (f32x4){0.f, 0.f, 0.f, 0.f};

    int arow = tid >> 3;            // 0..31
    int acol = (tid & 7) * 4;       // 0..28
    int brow = tid >> 2;            // 0..63
    int bcol = (tid & 3) * 8;       // 0..24

    for (int kk = 0; kk < DD; kk += BK) {
        // stage A tile (128 x 32 f32 -> bf16)
        #pragma unroll
        for (int p = 0; p < 4; ++p) {
            int r = p * 32 + arow;
            f32x4 v = *(const f32x4*)(A + (size_t)(m0 + r) * DD + kk + acol);
            ushort4 hv;
            hv.x = f2b(v.x); hv.y = f2b(v.y); hv.z = f2b(v.z); hv.w = f2b(v.w);
            *(ushort4*)(&As[r * PADK + acol]) = hv;
        }
        // stage BT tile (128 x 32 bf16)
        #pragma unroll
        for (int p = 0; p < 2; ++p) {
            int r = p * 64 + brow;
            bf16x8 v = *(const bf16x8*)(BT + (size_t)(n0 + r) * DD + kk + bcol);
            *(bf16x8*)(&Bs[r * PADK + bcol]) = v;
        }
        __syncthreads();

        bf16x8 af[4], bfr[4];
        #pragma unroll
        for (int m = 0; m < 4; ++m)
            af[m] = *(const bf16x8*)(&As[(wr + m * 16 + l15) * PADK + lk8]);
        #pragma unroll
        for (int n = 0; n < 4; ++n)
            bfr[n] = *(const bf16x8*)(&Bs[(wc + n * 16 + l15) * PADK + lk8]);

        #pragma unroll
        for (int m = 0; m < 4; ++m)
            #pragma unroll
            for (int n = 0; n < 4; ++n)
                acc[m][n] = __builtin_amdgcn_mfma_f32_16x16x32_bf16(
                    af[m], bfr[n], acc[m][n], 0, 0, 0);
        __syncthreads();
    }

    int r4 = (lane >> 4) * 4;
    #pragma unroll
    for (int m = 0; m < 4; ++m)
        #pragma unroll
        for (int n = 0; n < 4; ++n)
            #pragma unroll
            for (int j = 0; j < 4; ++j) {
                int row = m0 + wr + m * 16 + r4 + j;
                int col = n0 + wc + n * 16 + l15;
                C[(size_t)row * DD + col] = f2b(acc[m][n][j]);
            }
}

// ---------------------------------------------------------------------------
// out[r][0:512] = feats_a[r]; out[r][512:1024] = sum_k relu(P[r]+Q[idx_k]+bias)*w_k
// 64 lanes per row (8 cols each), 4 rows per 256-thread block
// ---------------------------------------------------------------------------
__global__ __launch_bounds__(256) void epilogue_kernel(
    const float* __restrict__ fa, const u16* __restrict__ Pb,
    const u16* __restrict__ Qb, const int* __restrict__ idxb,
    const float* __restrict__ wb, const float* __restrict__ bias,
    float* __restrict__ out) {

    int tid  = threadIdx.x;
    int r    = blockIdx.x * 4 + (tid >> 6);
    int lane = tid & 63;
    int c8   = lane * 8;
    int b    = r >> 11;

    const int*   ip = idxb + (size_t)r * 4;
    const float* wp = wb + (size_t)r * 4;
    int   i0 = ip[0], i1 = ip[1], i2 = ip[2], i3 = ip[3];
    float w0 = wp[0], w1 = wp[1], w2 = wp[2], w3 = wp[3];

    bf16x8 pv = *(const bf16x8*)(Pb + (size_t)r * DD + c8);
    f32x4 bia0 = *(const f32x4*)(bias + c8);
    f32x4 bia1 = *(const f32x4*)(bias + c8 + 4);

    float base[8], acc[8];
    #pragma unroll
    for (int j = 0; j < 8; ++j) {
        float bj = (j < 4) ? bia0[j] : bia1[j - 4];
        base[j] = b2f((u16)pv[j]) + bj;
        acc[j] = 0.f;
    }

    size_t qbase = ((size_t)b << 11) * DD;
    const u16* q0 = Qb + qbase + (size_t)i0 * DD + c8;
    const u16* q1 = Qb + qbase + (size_t)i1 * DD + c8;
    const u16* q2 = Qb + qbase + (size_t)i2 * DD + c8;
    const u16* q3 = Qb + qbase + (size_t)i3 * DD + c8;
    bf16x8 qv0 = *(const bf16x8*)q0;
    bf16x8 qv1 = *(const bf16x8*)q1;
    bf16x8 qv2 = *(const bf16x8*)q2;
    bf16x8 qv3 = *(const bf16x8*)q3;
    #pragma unroll
    for (int j = 0; j < 8; ++j) {
        acc[j] += fmaxf(base[j] + b2f((u16)qv0[j]), 0.f) * w0;
        acc[j] += fmaxf(base[j] + b2f((u16)qv1[j]), 0.f) * w1;
        acc[j] += fmaxf(base[j] + b2f((u16)qv2[j]), 0.f) * w2;
        acc[j] += fmaxf(base[j] + b2f((u16)qv3[j]), 0.f) * w3;
    }

    const float* ar = fa + (size_t)r * DD + c8;
    f32x4 a0 = *(const f32x4*)ar;
    f32x4 a1 = *(const f32x4*)(ar + 4);
    float* orow = out + (size_t)r * 1024;
    *(f32x4*)(orow + c8)     = a0;
    *(f32x4*)(orow + c8 + 4) = a1;
    f32x4 o0 = {acc[0], acc[1], acc[2], acc[3]};
    f32x4 o1 = {acc[4], acc[5], acc[6], acc[7]};
    *(f32x4*)(orow + 512 + c8)     = o0;
    *(f32x4*)(orow + 512 + c8 + 4) = o1;
}

extern "C" void kernel_launch(void* const* d_in, const int* in_sizes, int n_in,
                              void* d_out, int out_size, void* d_ws, size_t ws_size,
                              hipStream_t stream) {
    const float* fa   = (const float*)d_in[0];   // (16,2048,512) f32
    const float* fb   = (const float*)d_in[1];   // (16,2048,512) f32
    const float* W    = (const float*)d_in[2];   // (1024,512) f32
    const float* bias = (const float*)d_in[3];   // (512,) f32
    const int*   ca   = (const int*)d_in[4];     // (16,2048,3) i32
    const int*   cb   = (const int*)d_in[5];     // (16,2048,3) i32
    float* out = (float*)d_out;

    char* ws = (char*)d_ws;
    // ws layout (69,206,016 bytes total)
    u16*   Pb   = (u16*)(ws);                       // 32 MB  bf16 P
    u16*   Qb   = (u16*)(ws + 33554432);            // 32 MB  bf16 Q
    u16*   W2T  = (u16*)(ws + 67108864);            // 512 KB
    u16*   WdT  = (u16*)(ws + 67633152);            // 512 KB
    int*   idxb = (int*)(ws + 68157440);            // 512 KB
    float* wb   = (float*)(ws + 68681728);          // 512 KB

    prep_w<<<1024, 256, 0, stream>>>(W, W2T, WdT);

    dim3 tg(16, 16);
    topk_kernel<<<tg, 128, 0, stream>>>(ca, cb, idxb, wb);

    dim3 gg(256, 4);   // 32768/128 x 512/128
    gemm_f32xbt<<<gg, 256, 0, stream>>>(fa, W2T, Pb);
    gemm_f32xbt<<<gg, 256, 0, stream>>>(fb, WdT, Qb);

    epilogue_kernel<<<8192, 256, 0, stream>>>(fa, Pb, Qb, idxb, wb, bias, out);
}

// Round 2
// 161.510 us; speedup vs baseline: 1.3624x; 1.3624x over previous
//
#include <hip/hip_runtime.h>
#include <hip/hip_bf16.h>
#include <cstdint>
#include <cstddef>

#define NA   2048
#define NB   2048
#define DD   512
#define PADK 40

typedef __attribute__((ext_vector_type(8))) short bf16x8;
typedef __attribute__((ext_vector_type(4))) float f32x4;
typedef unsigned short u16;
typedef unsigned int   u32;

__device__ __forceinline__ u16 f2b_hw(float f) {
    u32 w;
    asm("v_cvt_pk_bf16_f32 %0, %1, %2" : "=v"(w) : "v"(f), "v"(f));
    return (u16)w;
}
__device__ __forceinline__ float b2f(u16 h) {
    return __uint_as_float(((u32)h) << 16);
}
__device__ __forceinline__ u32 umin32(u32 a, u32 b) { return a < b ? a : b; }
__device__ __forceinline__ u32 umax32(u32 a, u32 b) { return a > b ? a : b; }
__device__ __forceinline__ u32 med3u(u32 a, u32 b, u32 c) {
    return umax32(umin32(a, b), umin32(umax32(a, b), c));   // -> v_med3_u32
}

#define GLDS16(gsrc, ldst)                                                  \
    __builtin_amdgcn_global_load_lds(                                       \
        (const __attribute__((address_space(1))) void*)(gsrc),              \
        (__attribute__((address_space(3))) void*)(ldst), 16, 0, 0)

// ---------------------------------------------------------------------------
// Coalesced LDS-transpose: W2T[n][k]=W[512+k][n], WdT[n][k]=W[k][n]-W[512+k][n]
// ---------------------------------------------------------------------------
__global__ __launch_bounds__(256) void prep_w(const float* __restrict__ W,
                                              u16* __restrict__ W2T,
                                              u16* __restrict__ WdT) {
    __shared__ float s2[64][65];
    __shared__ float sd[64][65];
    int kb = blockIdx.x * 64, nb = blockIdx.y * 64;
    int tid = threadIdx.x;
    int c = tid & 63, r0 = tid >> 6;
    #pragma unroll
    for (int p = 0; p < 16; ++p) {
        int r = p * 4 + r0;
        float w1 = W[(size_t)(kb + r) * DD + nb + c];
        float w2 = W[(size_t)(512 + kb + r) * DD + nb + c];
        s2[r][c] = w2;
        sd[r][c] = w1 - w2;
    }
    __syncthreads();
    #pragma unroll
    for (int p = 0; p < 16; ++p) {
        int n = p * 4 + r0;
        W2T[(size_t)(nb + n) * DD + kb + c] = f2b_hw(s2[c][n]);
        WdT[(size_t)(nb + n) * DD + kb + c] = f2b_hw(sd[c][n]);
    }
}

// ---------------------------------------------------------------------------
// Exact integer top-4 NN, lax.top_k tie-break. key=(s<<11)|j.
// 512 threads: 4 j-groups x 128 queries, LDS merge. Packed coords, med3 insert.
// ---------------------------------------------------------------------------
__global__ __launch_bounds__(512) void topk_kernel(const int* __restrict__ ca,
                                                   const int* __restrict__ cb,
                                                   int* __restrict__ idx_out,
                                                   float* __restrict__ w_out) {
    __shared__ u32 pcb[NB];            // packed coords, 8KB
    __shared__ u32 part[3 * 128 * 4];  // partial top-4 of groups 1..3, 6KB
    int b = blockIdx.y;
    int tid = threadIdx.x;
    for (int p = tid; p < NB; p += 512) {
        const int* c = cb + ((size_t)b * NB + p) * 3;
        pcb[p] = (u32)c[0] | ((u32)c[1] << 8) | ((u32)c[2] << 16);
    }
    __syncthreads();

    int q = tid & 127, g = tid >> 7;
    int i = blockIdx.x * 128 + q;
    const int* ac = ca + ((size_t)b * NA + i) * 3;
    int ax = ac[0], ay = ac[1], az = ac[2];

    u32 k0 = ~0u, k1 = ~0u, k2 = ~0u, k3 = ~0u;
    int j0 = g * 512;
    #pragma unroll 8
    for (int jj = 0; jj < 512; ++jj) {
        int j = j0 + jj;
        u32 p = pcb[j];
        int dx = ax - (int)(p & 255u);
        int dy = ay - (int)((p >> 8) & 255u);
        int dz = az - (int)(p >> 16);
        u32 s = (u32)(__mul24(dx, dx) + __mul24(dy, dy) + __mul24(dz, dz));
        u32 key = (s << 11) | (u32)j;
        u32 nk0 = umin32(k0, key);
        u32 nk1 = med3u(key, k0, k1);
        u32 nk2 = med3u(key, k1, k2);
        u32 nk3 = med3u(key, k2, k3);
        k0 = nk0; k1 = nk1; k2 = nk2; k3 = nk3;
    }
    if (g) {
        u32* pp = &part[((g - 1) * 128 + q) * 4];
        pp[0] = k0; pp[1] = k1; pp[2] = k2; pp[3] = k3;
    }
    __syncthreads();
    if (g == 0) {
        #pragma unroll
        for (int L = 0; L < 3; ++L) {
            const u32* pp = &part[(L * 128 + q) * 4];
            #pragma unroll
            for (int t = 0; t < 4; ++t) {
                u32 key = pp[t];
                u32 nk0 = umin32(k0, key);
                u32 nk1 = med3u(key, k0, k1);
                u32 nk2 = med3u(key, k1, k2);
                u32 nk3 = med3u(key, k2, k3);
                k0 = nk0; k1 = nk1; k2 = nk2; k3 = nk3;
            }
        }
        size_t o = ((size_t)b * NA + i) * 4;
        u32 ks[4] = {k0, k1, k2, k3};
        #pragma unroll
        for (int t = 0; t < 4; ++t) {
            idx_out[o + t] = (int)(ks[t] & 2047u);
            float d = sqrtf((float)(ks[t] >> 11)) * (1.0f / 128.0f);
            w_out[o + t] = 0.5f - fminf(d, 0.5f);
        }
    }
}

// ---------------------------------------------------------------------------
// C (bf16) = A (f32) @ BT^T (bf16). 128x128 tile, BK=32, 4 waves.
// A: global_load_lds 16B with source-side XOR quad swizzle, f32 in LDS,
//    cvt to bf16 at fragment read. B: reg-staged, PADK pad.
// COPY: blocks also copy fa cols [n0,n0+128) into out[:,0:512] (L2-hot).
// ---------------------------------------------------------------------------
template<bool COPY>
__global__ __launch_bounds__(256) void gemm_kernel(const float* __restrict__ A,
                                                   const u16* __restrict__ BT,
                                                   u16* __restrict__ C,
                                                   float* __restrict__ outc) {
    __shared__ float As[128 * 32];     // 16KB, linear layout, swizzled content
    __shared__ u16  Bs[128 * PADK];    // 10KB

    const int tid  = threadIdx.x;
    const int lane = tid & 63;
    const int wave = tid >> 6;
    const int m0 = blockIdx.x * 128;
    const int n0 = blockIdx.y * 128;
    const int l15 = lane & 15;
    const int lk8 = (lane >> 4) * 8;        // k-offset of fragment: 0/8/16/24
    const int qa  = lk8 >> 2;               // f32 16B-quad index (even)

    const int srow  = lane >> 3;            // 0..7 (row within 8-row wave chunk)
    const int squad = (lane & 7) ^ srow;    // source-side swizzle

    const int brow = tid >> 2;
    const int bcol = (tid & 3) * 8;

    const int wr = (wave >> 1) * 64;
    const int wc = (wave & 1) * 64;

    f32x4 acc[4][4];
    #pragma unroll
    for (int m = 0; m < 4; ++m)
        #pragma unroll
        for (int n = 0; n < 4; ++n)
            acc[m][n] = (f32x4){0.f, 0.f, 0.f, 0.f};

    // constant per-lane LDS byte offsets for the A fragments (swizzled read)
    int aoff[4][2];
    #pragma unroll
    for (int m = 0; m < 4; ++m) {
        int R = wr + m * 16 + l15;
        int sx = R & 7;
        aoff[m][0] = R * 128 + ((qa ^ sx) << 4);
        aoff[m][1] = R * 128 + (((qa + 1) ^ sx) << 4);
    }
    const char* AsB = (const char*)As;

    const float* asrc[4];
    #pragma unroll
    for (int p = 0; p < 4; ++p)
        asrc[p] = A + (size_t)(m0 + p * 32 + wave * 8 + srow) * DD + squad * 4;
    const u16* bsrc[2];
    #pragma unroll
    for (int p = 0; p < 2; ++p)
        bsrc[p] = BT + (size_t)(n0 + p * 64 + brow) * DD + bcol;

    for (int kk = 0; kk < DD; kk += 32) {
        // B global loads first (latency), then async A staging
        bf16x8 bv0 = *(const bf16x8*)(bsrc[0] + kk);
        bf16x8 bv1 = *(const bf16x8*)(bsrc[1] + kk);
        #pragma unroll
        for (int p = 0; p < 4; ++p)
            GLDS16(asrc[p] + kk, As + (p * 32 + wave * 8) * 32);
        *(bf16x8*)(&Bs[brow * PADK + bcol]) = bv0;
        *(bf16x8*)(&Bs[(64 + brow) * PADK + bcol]) = bv1;

        if (COPY) {
            if (kk >= n0 && kk < n0 + 128) {
                #pragma unroll
                for (int p = 0; p < 4; ++p) {
                    int r = m0 + p * 32 + wave * 8 + srow;
                    f32x4 v = *(const f32x4*)(asrc[p] + kk);
                    *(f32x4*)(outc + (size_t)r * 1024 + kk + squad * 4) = v;
                }
            }
        }
        __syncthreads();

        bf16x8 af[4], bfr[4];
        #pragma unroll
        for (int m = 0; m < 4; ++m) {
            f32x4 lo = *(const f32x4*)(AsB + aoff[m][0]);
            f32x4 hi = *(const f32x4*)(AsB + aoff[m][1]);
            u32 w0, w1, w2, w3;
            asm("v_cvt_pk_bf16_f32 %0, %1, %2" : "=v"(w0) : "v"(lo[0]), "v"(lo[1]));
            asm("v_cvt_pk_bf16_f32 %0, %1, %2" : "=v"(w1) : "v"(lo[2]), "v"(lo[3]));
            asm("v_cvt_pk_bf16_f32 %0, %1, %2" : "=v"(w2) : "v"(hi[0]), "v"(hi[1]));
            asm("v_cvt_pk_bf16_f32 %0, %1, %2" : "=v"(w3) : "v"(hi[2]), "v"(hi[3]));
            union { u32 u[4]; bf16x8 v; } cv;
            cv.u[0] = w0; cv.u[1] = w1; cv.u[2] = w2; cv.u[3] = w3;
            af[m] = cv.v;
        }
        #pragma unroll
        for (int n = 0; n < 4; ++n)
            bfr[n] = *(const bf16x8*)(&Bs[(wc + n * 16 + l15) * PADK + lk8]);

        #pragma unroll
        for (int m = 0; m < 4; ++m)
            #pragma unroll
            for (int n = 0; n < 4; ++n)
                acc[m][n] = __builtin_amdgcn_mfma_f32_16x16x32_bf16(
                    af[m], bfr[n], acc[m][n], 0, 0, 0);
        __syncthreads();
    }

    const int r4 = (lane >> 4) * 4;
    #pragma unroll
    for (int m = 0; m < 4; ++m)
        #pragma unroll
        for (int n = 0; n < 4; ++n)
            #pragma unroll
            for (int j = 0; j < 4; ++j) {
                int row = m0 + wr + m * 16 + r4 + j;
                int col = n0 + wc + n * 16 + l15;
                C[(size_t)row * DD + col] = f2b_hw(acc[m][n][j]);
            }
}

// ---------------------------------------------------------------------------
// out[r][512:1024] = sum_k relu(P[r]+Q[idx_k]+bias)*w_k   (first half done by
// gemm<COPY>). XCD-swizzled so each XCD's Q working set = 2 batches = 4MB L2.
// ---------------------------------------------------------------------------
__global__ __launch_bounds__(256) void epilogue_kernel(
    const u16* __restrict__ Pb, const u16* __restrict__ Qb,
    const int* __restrict__ idxb, const float* __restrict__ wb,
    const float* __restrict__ bias, float* __restrict__ out) {

    int bid = blockIdx.x;
    int ob  = (bid & 7) * 1024 + (bid >> 3);   // bijective: 8192 = 8*1024
    int tid  = threadIdx.x;
    int r    = ob * 4 + (tid >> 6);
    int lane = tid & 63;
    int c8   = lane * 8;
    int b    = r >> 11;

    const int*   ip = idxb + (size_t)r * 4;
    const float* wp = wb + (size_t)r * 4;
    int   i0 = ip[0], i1 = ip[1], i2 = ip[2], i3 = ip[3];
    float w0 = wp[0], w1 = wp[1], w2 = wp[2], w3 = wp[3];

    bf16x8 pv = *(const bf16x8*)(Pb + (size_t)r * DD + c8);
    f32x4 bia0 = *(const f32x4*)(bias + c8);
    f32x4 bia1 = *(const f32x4*)(bias + c8 + 4);

    float base[8], acc[8];
    #pragma unroll
    for (int j = 0; j < 8; ++j) {
        float bj = (j < 4) ? bia0[j] : bia1[j - 4];
        base[j] = b2f((u16)pv[j]) + bj;
        acc[j] = 0.f;
    }

    size_t qbase = ((size_t)b << 11) * DD;
    bf16x8 qv0 = *(const bf16x8*)(Qb + qbase + (size_t)i0 * DD + c8);
    bf16x8 qv1 = *(const bf16x8*)(Qb + qbase + (size_t)i1 * DD + c8);
    bf16x8 qv2 = *(const bf16x8*)(Qb + qbase + (size_t)i2 * DD + c8);
    bf16x8 qv3 = *(const bf16x8*)(Qb + qbase + (size_t)i3 * DD + c8);
    #pragma unroll
    for (int j = 0; j < 8; ++j) {
        acc[j] += fmaxf(base[j] + b2f((u16)qv0[j]), 0.f) * w0;
        acc[j] += fmaxf(base[j] + b2f((u16)qv1[j]), 0.f) * w1;
        acc[j] += fmaxf(base[j] + b2f((u16)qv2[j]), 0.f) * w2;
        acc[j] += fmaxf(base[j] + b2f((u16)qv3[j]), 0.f) * w3;
    }

    float* orow = out + (size_t)r * 1024 + 512;
    f32x4 o0 = {acc[0], acc[1], acc[2], acc[3]};
    f32x4 o1 = {acc[4], acc[5], acc[6], acc[7]};
    *(f32x4*)(orow + c8)     = o0;
    *(f32x4*)(orow + c8 + 4) = o1;
}

extern "C" void kernel_launch(void* const* d_in, const int* in_sizes, int n_in,
                              void* d_out, int out_size, void* d_ws, size_t ws_size,
                              hipStream_t stream) {
    const float* fa   = (const float*)d_in[0];
    const float* fb   = (const float*)d_in[1];
    const float* W    = (const float*)d_in[2];
    const float* bias = (const float*)d_in[3];
    const int*   ca   = (const int*)d_in[4];
    const int*   cb   = (const int*)d_in[5];
    float* out = (float*)d_out;

    char* ws = (char*)d_ws;
    u16*   Pb   = (u16*)(ws);
    u16*   Qb   = (u16*)(ws + 33554432);
    u16*   W2T  = (u16*)(ws + 67108864);
    u16*   WdT  = (u16*)(ws + 67633152);
    int*   idxb = (int*)(ws + 68157440);
    float* wb   = (float*)(ws + 68681728);

    dim3 pg(8, 8);
    prep_w<<<pg, 256, 0, stream>>>(W, W2T, WdT);

    dim3 tg(16, 16);
    topk_kernel<<<tg, 512, 0, stream>>>(ca, cb, idxb, wb);

    dim3 gg(256, 4);
    gemm_kernel<true><<<gg, 256, 0, stream>>>(fa, W2T, Pb, out);
    gemm_kernel<false><<<gg, 256, 0, stream>>>(fb, WdT, Qb, nullptr);

    epilogue_kernel<<<8192, 256, 0, stream>>>(Pb, Qb, idxb, wb, bias, out);
}

// Round 3
// 152.506 us; speedup vs baseline: 1.4429x; 1.0590x over previous
//
#include <hip/hip_runtime.h>
#include <hip/hip_bf16.h>
#include <cstdint>
#include <cstddef>

#define NA   2048
#define NB   2048
#define DD   512
#define PADK 40

typedef __attribute__((ext_vector_type(8))) short bf16x8;
typedef __attribute__((ext_vector_type(4))) float f32x4;
typedef unsigned short u16;
typedef unsigned int   u32;

__device__ __forceinline__ u16 f2b_hw(float f) {
    u32 w;
    asm("v_cvt_pk_bf16_f32 %0, %1, %2" : "=v"(w) : "v"(f), "v"(f));
    return (u16)w;
}
__device__ __forceinline__ float b2f(u16 h) {
    return __uint_as_float(((u32)h) << 16);
}
__device__ __forceinline__ u32 umin32(u32 a, u32 b) { return a < b ? a : b; }
__device__ __forceinline__ u32 umax32(u32 a, u32 b) { return a > b ? a : b; }
__device__ __forceinline__ u32 med3u(u32 a, u32 b, u32 c) {
    return umax32(umin32(a, b), umin32(umax32(a, b), c));   // -> v_med3_u32
}

#define GLDS16(gsrc, ldst)                                                  \
    __builtin_amdgcn_global_load_lds(                                       \
        (const __attribute__((address_space(1))) void*)(gsrc),              \
        (__attribute__((address_space(3))) void*)(ldst), 16, 0, 0)

// ---------------------------------------------------------------------------
// Coalesced LDS-transpose: W2T[n][k]=W[512+k][n], WdT[n][k]=W[k][n]-W[512+k][n]
// ---------------------------------------------------------------------------
__global__ __launch_bounds__(256) void prep_w(const float* __restrict__ W,
                                              u16* __restrict__ W2T,
                                              u16* __restrict__ WdT) {
    __shared__ float s2[64][65];
    __shared__ float sd[64][65];
    int kb = blockIdx.x * 64, nb = blockIdx.y * 64;
    int tid = threadIdx.x;
    int c = tid & 63, r0 = tid >> 6;
    #pragma unroll
    for (int p = 0; p < 16; ++p) {
        int r = p * 4 + r0;
        float w1 = W[(size_t)(kb + r) * DD + nb + c];
        float w2 = W[(size_t)(512 + kb + r) * DD + nb + c];
        s2[r][c] = w2;
        sd[r][c] = w1 - w2;
    }
    __syncthreads();
    #pragma unroll
    for (int p = 0; p < 16; ++p) {
        int n = p * 4 + r0;
        W2T[(size_t)(nb + n) * DD + kb + c] = f2b_hw(s2[c][n]);
        WdT[(size_t)(nb + n) * DD + kb + c] = f2b_hw(sd[c][n]);
    }
}

// ---------------------------------------------------------------------------
// Exact integer top-4 NN (lax.top_k tie-break), plus fa -> out[:,0:512] copy
// (memory traffic hidden under the VALU-bound distance loop).
// ---------------------------------------------------------------------------
__global__ __launch_bounds__(512) void topk_kernel(const int* __restrict__ ca,
                                                   const int* __restrict__ cb,
                                                   int* __restrict__ idx_out,
                                                   float* __restrict__ w_out,
                                                   const float* __restrict__ fa,
                                                   float* __restrict__ out) {
    __shared__ u32 pcb[NB];            // packed coords, 8KB
    __shared__ u32 part[3 * 128 * 4];  // partial top-4 of groups 1..3, 6KB
    int b = blockIdx.y;
    int tid = threadIdx.x;
    for (int p = tid; p < NB; p += 512) {
        const int* c = cb + ((size_t)b * NB + p) * 3;
        pcb[p] = (u32)c[0] | ((u32)c[1] << 8) | ((u32)c[2] << 16);
    }
    __syncthreads();

    int q = tid & 127, g = tid >> 7;
    int i = blockIdx.x * 128 + q;
    const int* ac = ca + ((size_t)b * NA + i) * 3;
    int ax = ac[0], ay = ac[1], az = ac[2];

    u32 k0 = ~0u, k1 = ~0u, k2 = ~0u, k3 = ~0u;
    int j0 = g * 512;
    #pragma unroll 8
    for (int jj = 0; jj < 512; ++jj) {
        int j = j0 + jj;
        u32 p = pcb[j];
        int dx = ax - (int)(p & 255u);
        int dy = ay - (int)((p >> 8) & 255u);
        int dz = az - (int)(p >> 16);
        u32 s = (u32)(__mul24(dx, dx) + __mul24(dy, dy) + __mul24(dz, dz));
        u32 key = (s << 11) | (u32)j;
        u32 nk0 = umin32(k0, key);
        u32 nk1 = med3u(key, k0, k1);
        u32 nk2 = med3u(key, k1, k2);
        u32 nk3 = med3u(key, k2, k3);
        k0 = nk0; k1 = nk1; k2 = nk2; k3 = nk3;
    }
    if (g) {
        u32* pp = &part[((g - 1) * 128 + q) * 4];
        pp[0] = k0; pp[1] = k1; pp[2] = k2; pp[3] = k3;
    }
    __syncthreads();
    if (g == 0) {
        #pragma unroll
        for (int L = 0; L < 3; ++L) {
            const u32* pp = &part[(L * 128 + q) * 4];
            #pragma unroll
            for (int t = 0; t < 4; ++t) {
                u32 key = pp[t];
                u32 nk0 = umin32(k0, key);
                u32 nk1 = med3u(key, k0, k1);
                u32 nk2 = med3u(key, k1, k2);
                u32 nk3 = med3u(key, k2, k3);
                k0 = nk0; k1 = nk1; k2 = nk2; k3 = nk3;
            }
        }
        size_t o = ((size_t)b * NA + i) * 4;
        u32 ks[4] = {k0, k1, k2, k3};
        #pragma unroll
        for (int t = 0; t < 4; ++t) {
            idx_out[o + t] = (int)(ks[t] & 2047u);
            float d = sqrtf((float)(ks[t] >> 11)) * (1.0f / 128.0f);
            w_out[o + t] = 0.5f - fminf(d, 0.5f);
        }
    }

    // ---- fa -> out[:,0:512] copy: this block handles 128 rows ----
    int cid = blockIdx.y * gridDim.x + blockIdx.x;      // 0..255
    const float* src = fa + (size_t)cid * 128 * DD;
    float* dst = out + (size_t)cid * 128 * 1024;
    #pragma unroll 4
    for (int it = 0; it < 32; ++it) {
        int flat = it * 512 + tid;          // f32x4 index within 128x512 chunk
        int row = flat >> 7;
        int c4  = flat & 127;
        f32x4 v = *(const f32x4*)(src + (size_t)row * DD + c4 * 4);
        *(f32x4*)(dst + (size_t)row * 1024 + c4 * 4) = v;
    }
}

// ---------------------------------------------------------------------------
// C = A(f32->bf16) @ BT^T. 128x128 tile, BK=32, 4 waves, glds A w/ src swizzle.
// FUSED=false: write C (bf16)        -- used for Q = fb @ Wd^T
// FUSED=true : no C write; add bias, spill P-tile to LDS, gather Q[idx] rows,
//              write out[:,512+n0 .. 512+n0+128] directly -- used for P path.
// XCD-bijective m-swizzle: each XCD's rows = 2 batches -> Q slice fits its L2.
// ---------------------------------------------------------------------------
template<bool FUSED>
__global__ __launch_bounds__(256) void gemm_kernel(const float* __restrict__ A,
                                                   const u16* __restrict__ BT,
                                                   u16* __restrict__ C,
                                                   const int* __restrict__ idxb,
                                                   const float* __restrict__ wb,
                                                   const float* __restrict__ bias,
                                                   const u16* __restrict__ Qb,
                                                   float* __restrict__ out) {
    __shared__ __align__(16) char smem[FUSED ? 33792 : 26624];
    float* As = (float*)smem;                 // 128x32 f32, 16 KB (swizzled)
    u16*  Bs  = (u16*)(smem + 16384);         // 128xPADK bf16, 10 KB

    const int tid  = threadIdx.x;
    const int lane = tid & 63;
    const int wave = tid >> 6;
    const int mb   = blockIdx.x;
    const int m0 = (((mb & 7) << 5) | (mb >> 3)) * 128;   // bijective 8x32
    const int n0 = blockIdx.y * 128;
    const int l15 = lane & 15;
    const int lk8 = (lane >> 4) * 8;
    const int qa  = lk8 >> 2;

    const int srow  = lane >> 3;
    const int squad = (lane & 7) ^ srow;

    const int brow = tid >> 2;
    const int bcol = (tid & 3) * 8;

    const int wr = (wave >> 1) * 64;
    const int wc = (wave & 1) * 64;

    f32x4 acc[4][4];
    #pragma unroll
    for (int m = 0; m < 4; ++m)
        #pragma unroll
        for (int n = 0; n < 4; ++n)
            acc[m][n] = (f32x4){0.f, 0.f, 0.f, 0.f};

    int aoff[4][2];
    #pragma unroll
    for (int m = 0; m < 4; ++m) {
        int R = wr + m * 16 + l15;
        int sx = R & 7;
        aoff[m][0] = R * 128 + ((qa ^ sx) << 4);
        aoff[m][1] = R * 128 + (((qa + 1) ^ sx) << 4);
    }
    const char* AsB = (const char*)As;

    const float* asrc[4];
    #pragma unroll
    for (int p = 0; p < 4; ++p)
        asrc[p] = A + (size_t)(m0 + p * 32 + wave * 8 + srow) * DD + squad * 4;
    const u16* bsrc[2];
    #pragma unroll
    for (int p = 0; p < 2; ++p)
        bsrc[p] = BT + (size_t)(n0 + p * 64 + brow) * DD + bcol;

    for (int kk = 0; kk < DD; kk += 32) {
        bf16x8 bv0 = *(const bf16x8*)(bsrc[0] + kk);
        bf16x8 bv1 = *(const bf16x8*)(bsrc[1] + kk);
        #pragma unroll
        for (int p = 0; p < 4; ++p)
            GLDS16(asrc[p] + kk, As + (p * 32 + wave * 8) * 32);
        *(bf16x8*)(&Bs[brow * PADK + bcol]) = bv0;
        *(bf16x8*)(&Bs[(64 + brow) * PADK + bcol]) = bv1;
        __syncthreads();

        bf16x8 af[4], bfr[4];
        #pragma unroll
        for (int m = 0; m < 4; ++m) {
            f32x4 lo = *(const f32x4*)(AsB + aoff[m][0]);
            f32x4 hi = *(const f32x4*)(AsB + aoff[m][1]);
            u32 w0, w1, w2, w3;
            asm("v_cvt_pk_bf16_f32 %0, %1, %2" : "=v"(w0) : "v"(lo[0]), "v"(lo[1]));
            asm("v_cvt_pk_bf16_f32 %0, %1, %2" : "=v"(w1) : "v"(lo[2]), "v"(lo[3]));
            asm("v_cvt_pk_bf16_f32 %0, %1, %2" : "=v"(w2) : "v"(hi[0]), "v"(hi[1]));
            asm("v_cvt_pk_bf16_f32 %0, %1, %2" : "=v"(w3) : "v"(hi[2]), "v"(hi[3]));
            union { u32 u[4]; bf16x8 v; } cv;
            cv.u[0] = w0; cv.u[1] = w1; cv.u[2] = w2; cv.u[3] = w3;
            af[m] = cv.v;
        }
        #pragma unroll
        for (int n = 0; n < 4; ++n)
            bfr[n] = *(const bf16x8*)(&Bs[(wc + n * 16 + l15) * PADK + lk8]);

        #pragma unroll
        for (int m = 0; m < 4; ++m)
            #pragma unroll
            for (int n = 0; n < 4; ++n)
                acc[m][n] = __builtin_amdgcn_mfma_f32_16x16x32_bf16(
                    af[m], bfr[n], acc[m][n], 0, 0, 0);
        __syncthreads();
    }

    const int r4 = (lane >> 4) * 4;

    if (!FUSED) {
        #pragma unroll
        for (int m = 0; m < 4; ++m)
            #pragma unroll
            for (int n = 0; n < 4; ++n)
                #pragma unroll
                for (int j = 0; j < 4; ++j) {
                    int row = m0 + wr + m * 16 + r4 + j;
                    int col = n0 + wc + n * 16 + l15;
                    C[(size_t)row * DD + col] = f2b_hw(acc[m][n][j]);
                }
        return;
    }

    // ---- fused epilogue: P' = acc + bias -> LDS (bf16), then gather+out ----
    float bi[4];
    #pragma unroll
    for (int n = 0; n < 4; ++n)
        bi[n] = bias[n0 + wc + n * 16 + l15];

    u16* Ps = (u16*)smem;                     // [128][132] bf16, 33 KB
    #pragma unroll
    for (int m = 0; m < 4; ++m)
        #pragma unroll
        for (int n = 0; n < 4; ++n)
            #pragma unroll
            for (int j = 0; j < 4; ++j)
                Ps[(wr + m * 16 + r4 + j) * 132 + (wc + n * 16 + l15)] =
                    f2b_hw(acc[m][n][j] + bi[n]);
    __syncthreads();

    const int g = tid >> 4, l16 = tid & 15;
    const int bb = m0 >> 11;                                  // batch
    const u16* qs = Qb + ((size_t)bb << 20);                  // b*2048*512
    #pragma unroll
    for (int k = 0; k < 8; ++k) {
        const int r  = g * 8 + k;
        const int gr = m0 + r;
        int4  iv = *(const int4*)(idxb + (size_t)gr * 4);
        f32x4 wv = *(const f32x4*)(wb + (size_t)gr * 4);
        bf16x8 p8 = *(const bf16x8*)(Ps + r * 132 + l16 * 8);
        bf16x8 q0 = *(const bf16x8*)(qs + (size_t)iv.x * DD + n0 + l16 * 8);
        bf16x8 q1 = *(const bf16x8*)(qs + (size_t)iv.y * DD + n0 + l16 * 8);
        bf16x8 q2 = *(const bf16x8*)(qs + (size_t)iv.z * DD + n0 + l16 * 8);
        bf16x8 q3 = *(const bf16x8*)(qs + (size_t)iv.w * DD + n0 + l16 * 8);
        float o[8];
        #pragma unroll
        for (int j = 0; j < 8; ++j) {
            float p = b2f((u16)p8[j]);
            float s;
            s  = fmaxf(p + b2f((u16)q0[j]), 0.f) * wv[0];
            s += fmaxf(p + b2f((u16)q1[j]), 0.f) * wv[1];
            s += fmaxf(p + b2f((u16)q2[j]), 0.f) * wv[2];
            s += fmaxf(p + b2f((u16)q3[j]), 0.f) * wv[3];
            o[j] = s;
        }
        float* op = out + (size_t)gr * 1024 + 512 + n0 + l16 * 8;
        *(f32x4*)op       = (f32x4){o[0], o[1], o[2], o[3]};
        *(f32x4*)(op + 4) = (f32x4){o[4], o[5], o[6], o[7]};
    }
}

extern "C" void kernel_launch(void* const* d_in, const int* in_sizes, int n_in,
                              void* d_out, int out_size, void* d_ws, size_t ws_size,
                              hipStream_t stream) {
    const float* fa   = (const float*)d_in[0];
    const float* fb   = (const float*)d_in[1];
    const float* W    = (const float*)d_in[2];
    const float* bias = (const float*)d_in[3];
    const int*   ca   = (const int*)d_in[4];
    const int*   cb   = (const int*)d_in[5];
    float* out = (float*)d_out;

    char* ws = (char*)d_ws;
    u16*   Qb   = (u16*)(ws);                       // 32 MB bf16 Q
    u16*   W2T  = (u16*)(ws + 33554432);            // 512 KB
    u16*   WdT  = (u16*)(ws + 34078720);            // 512 KB
    int*   idxb = (int*)(ws + 34603008);            // 512 KB
    float* wb   = (float*)(ws + 35127296);          // 512 KB

    dim3 pg(8, 8);
    prep_w<<<pg, 256, 0, stream>>>(W, W2T, WdT);

    dim3 tg(16, 16);
    topk_kernel<<<tg, 512, 0, stream>>>(ca, cb, idxb, wb, fa, out);

    dim3 gg(256, 4);
    gemm_kernel<false><<<gg, 256, 0, stream>>>(fb, WdT, Qb, nullptr, nullptr,
                                               nullptr, nullptr, nullptr);
    gemm_kernel<true><<<gg, 256, 0, stream>>>(fa, W2T, nullptr, idxb, wb,
                                              bias, Qb, out);
}